// Round 1
// baseline (1121.614 us; speedup 1.0000x reference)
//
#include <hip/hip_runtime.h>
#include <math.h>

#define NH 16          // heads
#define HD 64          // head dim
#define NB 4           // batch
#define SQ 1024        // seq len
#define CH 1024        // channels

// ---------- helpers ----------
__device__ inline float waveSum(float v) {
    #pragma unroll
    for (int o = 1; o < 64; o <<= 1) v += __shfl_xor(v, o, 64);
    return v;
}
__device__ inline float waveMax(float v) {
    #pragma unroll
    for (int o = 1; o < 64; o <<= 1) v = fmaxf(v, __shfl_xor(v, o, 64));
    return v;
}

// ---------- 1) qkv = x @ W_qkv^T + b, scattered to q/k/v [B,H,N,D] ----------
__global__ __launch_bounds__(256) void k_qkv_gemm(
    const float* __restrict__ X, const float* __restrict__ W,
    const float* __restrict__ bias,
    float* __restrict__ q, float* __restrict__ k, float* __restrict__ v)
{
    __shared__ float As[64][17];
    __shared__ float Bs[64][17];
    const int tid = threadIdx.x;
    const int tx = tid & 15, ty = tid >> 4;
    const int m0 = blockIdx.y * 64;   // over B*N = 4096
    const int n0 = blockIdx.x * 64;   // over 3C = 3072

    float acc[4][4] = {};
    for (int k0 = 0; k0 < CH; k0 += 16) {
        const int r = tid >> 4, kk = tid & 15;
        #pragma unroll
        for (int i = 0; i < 4; ++i) {
            As[r + 16*i][kk] = X[(size_t)(m0 + r + 16*i) * CH + k0 + kk];
            Bs[r + 16*i][kk] = W[(size_t)(n0 + r + 16*i) * CH + k0 + kk];
        }
        __syncthreads();
        #pragma unroll
        for (int kk2 = 0; kk2 < 16; ++kk2) {
            float a[4], b[4];
            #pragma unroll
            for (int i = 0; i < 4; ++i) a[i] = As[ty + 16*i][kk2];
            #pragma unroll
            for (int j = 0; j < 4; ++j) b[j] = Bs[tx + 16*j][kk2];
            #pragma unroll
            for (int i = 0; i < 4; ++i)
                #pragma unroll
                for (int j = 0; j < 4; ++j) acc[i][j] += a[i] * b[j];
        }
        __syncthreads();
    }

    const int sec = n0 >> 10;            // 0=q 1=k 2=v
    float* dst = (sec == 0) ? q : (sec == 1) ? k : v;
    const int cbase = n0 & 1023;
    const int h = cbase >> 6;            // fixed per tile (tile spans exactly one head)
    #pragma unroll
    for (int i = 0; i < 4; ++i) {
        const int m = m0 + ty + 16*i;
        const int b_ = m >> 10, nn = m & 1023;
        #pragma unroll
        for (int j = 0; j < 4; ++j) {
            const int d = tx + 16*j;
            const int n = n0 + d;
            dst[(((size_t)(b_ * NH + h) * SQ + nn)) * HD + d]
                = acc[i][j] + bias[n];
        }
    }
}

// ---------- 2) LayerNorm on q (then *scale) and k, per row of 64 ----------
__global__ __launch_bounds__(256) void k_ln(
    float* __restrict__ q, float* __restrict__ k,
    const float* __restrict__ qg, const float* __restrict__ qb,
    const float* __restrict__ kg, const float* __restrict__ kb)
{
    const int wid = threadIdx.x >> 6, lane = threadIdx.x & 63;
    long long row = (long long)blockIdx.x * 4 + wid;   // 0 .. 131071
    float* p; const float* g; const float* bi; float scale;
    if (row < (long long)NB*NH*SQ) { p = q; g = qg; bi = qb; scale = 0.125f; }
    else { p = k; g = kg; bi = kb; scale = 1.0f; row -= (long long)NB*NH*SQ; }

    float x = p[row * HD + lane];
    const float m = waveSum(x) * (1.0f / 64.0f);
    const float d = x - m;
    const float var = waveSum(d * d) * (1.0f / 64.0f);
    const float y = d * rsqrtf(var + 1e-5f) * g[lane] + bi[lane];
    p[row * HD + lane] = y * scale;
}

// ---------- 3a) S = q @ k^T per (b,h), logits into weights buffer ----------
__global__ __launch_bounds__(256) void k_qk(
    const float* __restrict__ q, const float* __restrict__ k,
    float* __restrict__ S)
{
    __shared__ float Qs[64][65];
    __shared__ float Ks[64][65];
    const int bh = blockIdx.z;
    const float* qb = q + (size_t)bh * SQ * HD;
    const float* kb = k + (size_t)bh * SQ * HD;
    const int r0 = blockIdx.y * 64, c0 = blockIdx.x * 64;
    const int tid = threadIdx.x;

    #pragma unroll
    for (int i = 0; i < 16; ++i) {
        const int e = tid + i * 256;
        const int rr = e >> 6, cc = e & 63;
        Qs[rr][cc] = qb[(size_t)(r0 + rr) * HD + cc];
        Ks[rr][cc] = kb[(size_t)(c0 + rr) * HD + cc];
    }
    __syncthreads();

    const int tx = tid & 15, ty = tid >> 4;
    float acc[4][4] = {};
    #pragma unroll
    for (int kk = 0; kk < 64; ++kk) {
        float a[4], b[4];
        #pragma unroll
        for (int i = 0; i < 4; ++i) a[i] = Qs[ty + 16*i][kk];
        #pragma unroll
        for (int j = 0; j < 4; ++j) b[j] = Ks[tx + 16*j][kk];
        #pragma unroll
        for (int i = 0; i < 4; ++i)
            #pragma unroll
            for (int j = 0; j < 4; ++j) acc[i][j] += a[i] * b[j];
    }
    float* Sp = S + (size_t)bh * SQ * SQ;
    #pragma unroll
    for (int i = 0; i < 4; ++i)
        #pragma unroll
        for (int j = 0; j < 4; ++j)
            Sp[(size_t)(r0 + ty + 16*i) * SQ + c0 + tx + 16*j] = acc[i][j];
}

// ---------- 3b) row softmax in place ----------
__global__ __launch_bounds__(256) void k_softmax(float* __restrict__ S)
{
    const size_t base = (size_t)blockIdx.x * SQ;
    const int tid = threadIdx.x;
    float x[4];
    float m = -INFINITY;
    #pragma unroll
    for (int i = 0; i < 4; ++i) {
        x[i] = S[base + tid + i * 256];
        m = fmaxf(m, x[i]);
    }
    m = waveMax(m);
    __shared__ float redm[4];
    if ((tid & 63) == 0) redm[tid >> 6] = m;
    __syncthreads();
    m = fmaxf(fmaxf(redm[0], redm[1]), fmaxf(redm[2], redm[3]));

    float s = 0.0f;
    #pragma unroll
    for (int i = 0; i < 4; ++i) { x[i] = __expf(x[i] - m); s += x[i]; }
    s = waveSum(s);
    __shared__ float reds[4];
    if ((tid & 63) == 0) reds[tid >> 6] = s;
    __syncthreads();
    s = reds[0] + reds[1] + reds[2] + reds[3];
    const float inv = 1.0f / s;
    #pragma unroll
    for (int i = 0; i < 4; ++i) S[base + tid + i * 256] = x[i] * inv;
}

// ---------- 3c) out_pre[b,n,h*64+d] = P @ v ----------
__global__ __launch_bounds__(256) void k_pv(
    const float* __restrict__ P, const float* __restrict__ v,
    float* __restrict__ outp)
{
    __shared__ float Ps[64][65];
    __shared__ float Vs[64][65];
    const int bh = blockIdx.y;
    const int r0 = blockIdx.x * 64;
    const float* Pb = P + (size_t)bh * SQ * SQ;
    const float* vb = v + (size_t)bh * SQ * HD;
    const int tid = threadIdx.x, tx = tid & 15, ty = tid >> 4;

    float acc[4][4] = {};
    for (int k0 = 0; k0 < SQ; k0 += 64) {
        #pragma unroll
        for (int i = 0; i < 16; ++i) {
            const int e = tid + i * 256;
            const int rr = e >> 6, cc = e & 63;
            Ps[rr][cc] = Pb[(size_t)(r0 + rr) * SQ + k0 + cc];
            Vs[rr][cc] = vb[(size_t)(k0 + rr) * HD + cc];
        }
        __syncthreads();
        #pragma unroll
        for (int kk = 0; kk < 64; ++kk) {
            float a[4], b[4];
            #pragma unroll
            for (int i = 0; i < 4; ++i) a[i] = Ps[ty + 16*i][kk];
            #pragma unroll
            for (int j = 0; j < 4; ++j) b[j] = Vs[kk][tx + 16*j];
            #pragma unroll
            for (int i = 0; i < 4; ++i)
                #pragma unroll
                for (int j = 0; j < 4; ++j) acc[i][j] += a[i] * b[j];
        }
        __syncthreads();
    }
    const int b_ = bh >> 4, h = bh & 15;
    #pragma unroll
    for (int i = 0; i < 4; ++i) {
        const int row = r0 + ty + 16*i;
        #pragma unroll
        for (int j = 0; j < 4; ++j) {
            const int d = tx + 16*j;
            outp[((size_t)(b_ * SQ + row)) * CH + h * HD + d] = acc[i][j];
        }
    }
}

// ---------- 4) out = out_pre @ W_proj^T + b_proj ----------
__global__ __launch_bounds__(256) void k_proj(
    const float* __restrict__ A, const float* __restrict__ W,
    const float* __restrict__ bias, float* __restrict__ out)
{
    __shared__ float As[64][17];
    __shared__ float Bs[64][17];
    const int tid = threadIdx.x;
    const int tx = tid & 15, ty = tid >> 4;
    const int m0 = blockIdx.y * 64;   // over 4096
    const int n0 = blockIdx.x * 64;   // over 1024

    float acc[4][4] = {};
    for (int k0 = 0; k0 < CH; k0 += 16) {
        const int r = tid >> 4, kk = tid & 15;
        #pragma unroll
        for (int i = 0; i < 4; ++i) {
            As[r + 16*i][kk] = A[(size_t)(m0 + r + 16*i) * CH + k0 + kk];
            Bs[r + 16*i][kk] = W[(size_t)(n0 + r + 16*i) * CH + k0 + kk];
        }
        __syncthreads();
        #pragma unroll
        for (int kk2 = 0; kk2 < 16; ++kk2) {
            float a[4], b[4];
            #pragma unroll
            for (int i = 0; i < 4; ++i) a[i] = As[ty + 16*i][kk2];
            #pragma unroll
            for (int j = 0; j < 4; ++j) b[j] = Bs[tx + 16*j][kk2];
            #pragma unroll
            for (int i = 0; i < 4; ++i)
                #pragma unroll
                for (int j = 0; j < 4; ++j) acc[i][j] += a[i] * b[j];
        }
        __syncthreads();
    }
    #pragma unroll
    for (int i = 0; i < 4; ++i) {
        const int m = m0 + ty + 16*i;
        #pragma unroll
        for (int j = 0; j < 4; ++j) {
            const int n = n0 + tx + 16*j;
            out[(size_t)m * CH + n] = acc[i][j] + bias[n];
        }
    }
}

extern "C" void kernel_launch(void* const* d_in, const int* in_sizes, int n_in,
                              void* d_out, int out_size, void* d_ws, size_t ws_size,
                              hipStream_t stream)
{
    const float* x    = (const float*)d_in[0];
    const float* Wqkv = (const float*)d_in[1];
    const float* bqkv = (const float*)d_in[2];
    const float* qg   = (const float*)d_in[3];
    const float* qb   = (const float*)d_in[4];
    const float* kg   = (const float*)d_in[5];
    const float* kb   = (const float*)d_in[6];
    const float* Wp   = (const float*)d_in[7];
    const float* bp   = (const float*)d_in[8];

    float* out     = (float*)d_out;                       // [B,N,C] = 4M floats
    float* weights = out + (size_t)NB * SQ * CH;          // [B,H,N,N] = 64M floats

    float* q    = (float*)d_ws;                           // [B,H,N,D] 4M floats
    float* k    = q + (size_t)NB * NH * SQ * HD;          // 4M floats
    float* v    = k + (size_t)NB * NH * SQ * HD;          // 4M floats
    float* outp = q;                                      // alias: q dead after k_qk

    // 1) qkv GEMM: M=4096, N=3072, K=1024
    k_qkv_gemm<<<dim3(48, 64), 256, 0, stream>>>(x, Wqkv, bqkv, q, k, v);
    // 2) LN on q (scaled) and k: 131072 rows, 4 rows/block
    k_ln<<<32768, 256, 0, stream>>>(q, k, qg, qb, kg, kb);
    // 3a) logits into weights buffer
    k_qk<<<dim3(16, 16, NB * NH), 256, 0, stream>>>(q, k, weights);
    // 3b) softmax in place
    k_softmax<<<NB * NH * SQ, 256, 0, stream>>>(weights);
    // 3c) PV into pre-proj activations
    k_pv<<<dim3(16, NB * NH), 256, 0, stream>>>(weights, v, outp);
    // 4) proj GEMM
    k_proj<<<dim3(16, 64), 256, 0, stream>>>(outp, Wp, bp, out);
}

// Round 3
// 679.807 us; speedup vs baseline: 1.6499x; 1.6499x over previous
//
#include <hip/hip_runtime.h>
#include <math.h>

#define NH 16          // heads
#define HD 64          // head dim
#define NB 4           // batch
#define SQ 1024        // seq len
#define CH 1024        // channels

typedef __bf16 bf16x8 __attribute__((ext_vector_type(8)));
typedef __bf16 bf16x4 __attribute__((ext_vector_type(4)));
typedef float  f32x4  __attribute__((ext_vector_type(4)));

typedef const __attribute__((address_space(1))) void gvoid_t;
typedef __attribute__((address_space(3))) void lvoid_t;

// ---------- helpers ----------
__device__ inline float waveSum(float v) {
    #pragma unroll
    for (int o = 1; o < 64; o <<= 1) v += __shfl_xor(v, o, 64);
    return v;
}
__device__ inline float waveMax(float v) {
    #pragma unroll
    for (int o = 1; o < 64; o <<= 1) v = fmaxf(v, __shfl_xor(v, o, 64));
    return v;
}

// ---------- split fp32 -> bf16 hi/lo ----------
__global__ __launch_bounds__(256) void k_split(
    const float* __restrict__ in, __bf16* __restrict__ hi,
    __bf16* __restrict__ lo, int n4)
{
    const int idx = blockIdx.x * 256 + threadIdx.x;
    if (idx >= n4) return;
    const float4 v = ((const float4*)in)[idx];
    bf16x4 h, l;
    h[0] = (__bf16)v.x; l[0] = (__bf16)(v.x - (float)h[0]);
    h[1] = (__bf16)v.y; l[1] = (__bf16)(v.y - (float)h[1]);
    h[2] = (__bf16)v.z; l[2] = (__bf16)(v.z - (float)h[2]);
    h[3] = (__bf16)v.w; l[3] = (__bf16)(v.w - (float)h[3]);
    ((bf16x4*)hi)[idx] = h;
    ((bf16x4*)lo)[idx] = l;
}

// ---------- split-bf16 MFMA GEMM: C = A @ B^T (+bias), A[M][1024], B[N][1024]
// EPI 0: scatter to q/k/v [B,H,N,D].  EPI 1: plain out [M][1024]. ----------
template<int EPI>
__global__ __launch_bounds__(256) void k_mfma_gemm(
    const __bf16* __restrict__ Ah, const __bf16* __restrict__ Al,
    const __bf16* __restrict__ Bh, const __bf16* __restrict__ Bl,
    const float* __restrict__ bias,
    float* __restrict__ o0, float* __restrict__ o1, float* __restrict__ o2)
{
    __shared__ __align__(16) __bf16 sAh[128 * 32];
    __shared__ __align__(16) __bf16 sAl[128 * 32];
    __shared__ __align__(16) __bf16 sBh[128 * 32];
    __shared__ __align__(16) __bf16 sBl[128 * 32];

    const int tid = threadIdx.x;
    const int wid = tid >> 6, lane = tid & 63;
    const int wr = wid >> 1, wc = wid & 1;
    const int m0 = blockIdx.y * 128, n0 = blockIdx.x * 128;

    f32x4 acc[4][4];
    #pragma unroll
    for (int i = 0; i < 4; ++i)
        #pragma unroll
        for (int j = 0; j < 4; ++j)
            acc[i][j] = (f32x4){0.f, 0.f, 0.f, 0.f};

    // each wave stages one array
    const __bf16* gsrc = (wid == 0) ? Ah : (wid == 1) ? Al : (wid == 2) ? Bh : Bl;
    __bf16* sdst = (wid == 0) ? sAh : (wid == 1) ? sAl : (wid == 2) ? sBh : sBl;
    const int gbase = (wid < 2) ? m0 : n0;
    const int grow = gbase + (lane >> 2);      // + i*16
    const int gcol = (lane & 3) * 8;           // 8 bf16 = 16B per lane

    const int arow = wr * 64 + (lane & 15);
    const int brow = wc * 64 + (lane & 15);
    const int koff = (lane >> 4) * 8;

    for (int k0 = 0; k0 < CH; k0 += 32) {
        #pragma unroll
        for (int i = 0; i < 8; ++i) {
            const __bf16* g = gsrc + (size_t)(grow + i * 16) * CH + k0 + gcol;
            __builtin_amdgcn_global_load_lds((gvoid_t*)g,
                                             (lvoid_t*)(sdst + i * 512),
                                             16, 0, 0);
        }
        __syncthreads();

        bf16x8 a_h[4], a_l[4], b_h[4], b_l[4];
        #pragma unroll
        for (int f = 0; f < 4; ++f) {
            a_h[f] = *(const bf16x8*)&sAh[(arow + f * 16) * 32 + koff];
            a_l[f] = *(const bf16x8*)&sAl[(arow + f * 16) * 32 + koff];
            b_h[f] = *(const bf16x8*)&sBh[(brow + f * 16) * 32 + koff];
            b_l[f] = *(const bf16x8*)&sBl[(brow + f * 16) * 32 + koff];
        }
        #pragma unroll
        for (int i = 0; i < 4; ++i)
            #pragma unroll
            for (int j = 0; j < 4; ++j) {
                acc[i][j] = __builtin_amdgcn_mfma_f32_16x16x32_bf16(a_h[i], b_l[j], acc[i][j], 0, 0, 0);
                acc[i][j] = __builtin_amdgcn_mfma_f32_16x16x32_bf16(a_l[i], b_h[j], acc[i][j], 0, 0, 0);
                acc[i][j] = __builtin_amdgcn_mfma_f32_16x16x32_bf16(a_h[i], b_h[j], acc[i][j], 0, 0, 0);
            }
        __syncthreads();
    }

    const int crow = (lane >> 4) * 4;
    const int ccol = lane & 15;
    #pragma unroll
    for (int i = 0; i < 4; ++i) {
        #pragma unroll
        for (int j = 0; j < 4; ++j) {
            const int n = n0 + wc * 64 + j * 16 + ccol;
            const float bv = bias[n];
            if (EPI == 0) {
                const int sec = n >> 10, h = (n & 1023) >> 6, d = n & 63;
                float* dst = (sec == 0) ? o0 : (sec == 1) ? o1 : o2;
                #pragma unroll
                for (int r = 0; r < 4; ++r) {
                    const int m = m0 + wr * 64 + i * 16 + crow + r;
                    const int b_ = m >> 10, nn = m & 1023;
                    dst[((size_t)(b_ * NH + h) * SQ + nn) * HD + d] = acc[i][j][r] + bv;
                }
            } else {
                #pragma unroll
                for (int r = 0; r < 4; ++r) {
                    const int m = m0 + wr * 64 + i * 16 + crow + r;
                    o0[(size_t)m * CH + n] = acc[i][j][r] + bv;
                }
            }
        }
    }
}

// ---------- LayerNorm on q (then *scale) and k ----------
__global__ __launch_bounds__(256) void k_ln(
    float* __restrict__ q, float* __restrict__ k,
    const float* __restrict__ qg, const float* __restrict__ qb,
    const float* __restrict__ kg, const float* __restrict__ kb)
{
    const int wid = threadIdx.x >> 6, lane = threadIdx.x & 63;
    long long row = (long long)blockIdx.x * 4 + wid;
    float* p; const float* g; const float* bi; float scale;
    if (row < (long long)NB * NH * SQ) { p = q; g = qg; bi = qb; scale = 0.125f; }
    else { p = k; g = kg; bi = kb; scale = 1.0f; row -= (long long)NB * NH * SQ; }

    float x = p[row * HD + lane];
    const float m = waveSum(x) * (1.0f / 64.0f);
    const float d = x - m;
    const float var = waveSum(d * d) * (1.0f / 64.0f);
    const float y = d * rsqrtf(var + 1e-5f) * g[lane] + bi[lane];
    p[row * HD + lane] = y * scale;
}

// ---------- S = q @ k^T per (b,h) ----------
__global__ __launch_bounds__(256) void k_qk(
    const float* __restrict__ q, const float* __restrict__ k,
    float* __restrict__ S)
{
    __shared__ float Qs[64][65];
    __shared__ float Ks[64][65];
    const int bh = blockIdx.z;
    const float* qb = q + (size_t)bh * SQ * HD;
    const float* kb = k + (size_t)bh * SQ * HD;
    const int r0 = blockIdx.y * 64, c0 = blockIdx.x * 64;
    const int tid = threadIdx.x;

    #pragma unroll
    for (int i = 0; i < 16; ++i) {
        const int e = tid + i * 256;
        const int rr = e >> 6, cc = e & 63;
        Qs[rr][cc] = qb[(size_t)(r0 + rr) * HD + cc];
        Ks[rr][cc] = kb[(size_t)(c0 + rr) * HD + cc];
    }
    __syncthreads();

    const int tx = tid & 15, ty = tid >> 4;
    float acc[4][4] = {};
    #pragma unroll
    for (int kk = 0; kk < 64; ++kk) {
        float a[4], b[4];
        #pragma unroll
        for (int i = 0; i < 4; ++i) a[i] = Qs[ty + 16*i][kk];
        #pragma unroll
        for (int j = 0; j < 4; ++j) b[j] = Ks[tx + 16*j][kk];
        #pragma unroll
        for (int i = 0; i < 4; ++i)
            #pragma unroll
            for (int j = 0; j < 4; ++j) acc[i][j] += a[i] * b[j];
    }
    float* Sp = S + (size_t)bh * SQ * SQ;
    #pragma unroll
    for (int i = 0; i < 4; ++i)
        #pragma unroll
        for (int j = 0; j < 4; ++j)
            Sp[(size_t)(r0 + ty + 16*i) * SQ + c0 + tx + 16*j] = acc[i][j];
}

// ---------- row softmax in place ----------
__global__ __launch_bounds__(256) void k_softmax(float* __restrict__ S)
{
    const size_t base = (size_t)blockIdx.x * SQ;
    const int tid = threadIdx.x;
    float x[4];
    float m = -INFINITY;
    #pragma unroll
    for (int i = 0; i < 4; ++i) {
        x[i] = S[base + tid + i * 256];
        m = fmaxf(m, x[i]);
    }
    m = waveMax(m);
    __shared__ float redm[4];
    if ((tid & 63) == 0) redm[tid >> 6] = m;
    __syncthreads();
    m = fmaxf(fmaxf(redm[0], redm[1]), fmaxf(redm[2], redm[3]));

    float s = 0.0f;
    #pragma unroll
    for (int i = 0; i < 4; ++i) { x[i] = __expf(x[i] - m); s += x[i]; }
    s = waveSum(s);
    __shared__ float reds[4];
    if ((tid & 63) == 0) reds[tid >> 6] = s;
    __syncthreads();
    s = reds[0] + reds[1] + reds[2] + reds[3];
    const float inv = 1.0f / s;
    #pragma unroll
    for (int i = 0; i < 4; ++i) S[base + tid + i * 256] = x[i] * inv;
}

// ---------- out_pre = P @ v, written as bf16 hi/lo for the proj MFMA ----------
__global__ __launch_bounds__(256) void k_pv(
    const float* __restrict__ P, const float* __restrict__ v,
    __bf16* __restrict__ oph, __bf16* __restrict__ opl)
{
    __shared__ float Ps[64][65];
    __shared__ float Vs[64][65];
    const int bh = blockIdx.y;
    const int r0 = blockIdx.x * 64;
    const float* Pb = P + (size_t)bh * SQ * SQ;
    const float* vb = v + (size_t)bh * SQ * HD;
    const int tid = threadIdx.x, tx = tid & 15, ty = tid >> 4;

    float acc[4][4] = {};
    for (int k0 = 0; k0 < SQ; k0 += 64) {
        #pragma unroll
        for (int i = 0; i < 16; ++i) {
            const int e = tid + i * 256;
            const int rr = e >> 6, cc = e & 63;
            Ps[rr][cc] = Pb[(size_t)(r0 + rr) * SQ + k0 + cc];
            Vs[rr][cc] = vb[(size_t)(k0 + rr) * HD + cc];
        }
        __syncthreads();
        #pragma unroll
        for (int kk = 0; kk < 64; ++kk) {
            float a[4], b[4];
            #pragma unroll
            for (int i = 0; i < 4; ++i) a[i] = Ps[ty + 16*i][kk];
            #pragma unroll
            for (int j = 0; j < 4; ++j) b[j] = Vs[kk][tx + 16*j];
            #pragma unroll
            for (int i = 0; i < 4; ++i)
                #pragma unroll
                for (int j = 0; j < 4; ++j) acc[i][j] += a[i] * b[j];
        }
        __syncthreads();
    }
    const int b_ = bh >> 4, h = bh & 15;
    #pragma unroll
    for (int i = 0; i < 4; ++i) {
        const int row = r0 + ty + 16*i;
        #pragma unroll
        for (int j = 0; j < 4; ++j) {
            const int d = tx + 16*j;
            const size_t idx = ((size_t)(b_ * SQ + row)) * CH + h * HD + d;
            const float val = acc[i][j];
            const __bf16 hh = (__bf16)val;
            oph[idx] = hh;
            opl[idx] = (__bf16)(val - (float)hh);
        }
    }
}

extern "C" void kernel_launch(void* const* d_in, const int* in_sizes, int n_in,
                              void* d_out, int out_size, void* d_ws, size_t ws_size,
                              hipStream_t stream)
{
    const float* x    = (const float*)d_in[0];
    const float* Wqkv = (const float*)d_in[1];
    const float* bqkv = (const float*)d_in[2];
    const float* qg   = (const float*)d_in[3];
    const float* qb   = (const float*)d_in[4];
    const float* kg   = (const float*)d_in[5];
    const float* kb   = (const float*)d_in[6];
    const float* Wp   = (const float*)d_in[7];
    const float* bp   = (const float*)d_in[8];

    float* out     = (float*)d_out;                       // [B,N,C]
    float* weights = out + (size_t)NB * SQ * CH;          // [B,H,N,N]

    // workspace layout (bytes):
    //   q,k,v fp32: 3 x 16MB = 48MB
    //   xh,xl bf16: 8MB each (oph/opl alias these after qkv GEMM)
    //   wqh,wql bf16: 6MB each ; wph,wpl bf16: 2MB each   -> total 80MB
    char* w = (char*)d_ws;
    float*  q   = (float*)w;                                  // 16MB
    float*  k   = (float*)(w + (((size_t)16) << 20));         // 16MB
    float*  v   = (float*)(w + (((size_t)32) << 20));         // 16MB
    __bf16* xh  = (__bf16*)(w + (((size_t)48) << 20));        // 8MB
    __bf16* xl  = (__bf16*)(w + (((size_t)56) << 20));        // 8MB
    __bf16* wqh = (__bf16*)(w + (((size_t)64) << 20));        // 6MB
    __bf16* wql = (__bf16*)(w + (((size_t)70) << 20));        // 6MB
    __bf16* wph = (__bf16*)(w + (((size_t)76) << 20));        // 2MB
    __bf16* wpl = (__bf16*)(w + (((size_t)78) << 20));        // 2MB
    __bf16* oph = xh;                                         // alias (x dead)
    __bf16* opl = xl;

    // 0) split inputs to bf16 hi/lo
    k_split<<<(NB*SQ*CH/4 + 255)/256, 256, 0, stream>>>(x, xh, xl, NB*SQ*CH/4);
    k_split<<<(3*CH*CH/4 + 255)/256, 256, 0, stream>>>(Wqkv, wqh, wql, 3*CH*CH/4);
    k_split<<<(CH*CH/4 + 255)/256, 256, 0, stream>>>(Wp, wph, wpl, CH*CH/4);

    // 1) qkv GEMM (MFMA): M=4096, N=3072, K=1024 -> scatter q/k/v
    k_mfma_gemm<0><<<dim3(24, 32), 256, 0, stream>>>(xh, xl, wqh, wql, bqkv, q, k, v);

    // 2) LN on q (scaled) and k
    k_ln<<<32768, 256, 0, stream>>>(q, k, qg, qb, kg, kb);

    // 3a) logits into weights buffer
    k_qk<<<dim3(16, 16, NB * NH), 256, 0, stream>>>(q, k, weights);

    // 3b) softmax in place
    k_softmax<<<NB * NH * SQ, 256, 0, stream>>>(weights);

    // 3c) PV -> pre-proj activations as bf16 hi/lo
    k_pv<<<dim3(16, NB * NH), 256, 0, stream>>>(weights, v, oph, opl);

    // 4) proj GEMM (MFMA): M=4096, N=1024, K=1024
    k_mfma_gemm<1><<<dim3(8, 32), 256, 0, stream>>>(oph, opl, wph, wpl, bp, out, nullptr, nullptr);
}

// Round 4
// 355.599 us; speedup vs baseline: 3.1542x; 1.9117x over previous
//
#include <hip/hip_runtime.h>
#include <math.h>

#define NH 16          // heads
#define HD 64          // head dim
#define NB 4           // batch
#define SQ 1024        // seq len
#define CH 1024        // channels

typedef __bf16   bf16x8 __attribute__((ext_vector_type(8)));
typedef __bf16   bf16x4 __attribute__((ext_vector_type(4)));
typedef _Float16 f16x8  __attribute__((ext_vector_type(8)));
typedef _Float16 f16x4  __attribute__((ext_vector_type(4)));
typedef float    f32x4  __attribute__((ext_vector_type(4)));

typedef const __attribute__((address_space(1))) void gvoid_t;
typedef __attribute__((address_space(3))) void lvoid_t;

// ---------- split fp32 -> bf16 hi/lo ----------
__global__ __launch_bounds__(256) void k_split(
    const float* __restrict__ in, __bf16* __restrict__ hi,
    __bf16* __restrict__ lo, int n4)
{
    const int idx = blockIdx.x * 256 + threadIdx.x;
    if (idx >= n4) return;
    const float4 v = ((const float4*)in)[idx];
    bf16x4 h, l;
    h[0] = (__bf16)v.x; l[0] = (__bf16)(v.x - (float)h[0]);
    h[1] = (__bf16)v.y; l[1] = (__bf16)(v.y - (float)h[1]);
    h[2] = (__bf16)v.z; l[2] = (__bf16)(v.z - (float)h[2]);
    h[3] = (__bf16)v.w; l[3] = (__bf16)(v.w - (float)h[3]);
    ((bf16x4*)hi)[idx] = h;
    ((bf16x4*)lo)[idx] = l;
}

// ---------- split-bf16 MFMA GEMM: C = A @ B^T (+bias)
// EPI 0: fused LN epilogue -> q,k fp16 [B,H,N,D] (LN'd, q scaled), vT fp16 [B,H,D,N]
// EPI 1: plain fp32 out [M][1024] ----------
template<int EPI>
__global__ __launch_bounds__(256) void k_mfma_gemm(
    const __bf16* __restrict__ Ah, const __bf16* __restrict__ Al,
    const __bf16* __restrict__ Bh, const __bf16* __restrict__ Bl,
    const float* __restrict__ bias, float* __restrict__ outp,
    _Float16* __restrict__ qf, _Float16* __restrict__ kf, _Float16* __restrict__ vTf,
    const float* __restrict__ qg, const float* __restrict__ qb_,
    const float* __restrict__ kg, const float* __restrict__ kb_)
{
    __shared__ __align__(16) __bf16 sAh[128 * 32];
    __shared__ __align__(16) __bf16 sAl[128 * 32];
    __shared__ __align__(16) __bf16 sBh[128 * 32];
    __shared__ __align__(16) __bf16 sBl[128 * 32];

    const int tid = threadIdx.x;
    const int wid = tid >> 6, lane = tid & 63;
    const int wr = wid >> 1, wc = wid & 1;
    const int m0 = blockIdx.y * 128, n0 = blockIdx.x * 128;

    f32x4 acc[4][4];
    #pragma unroll
    for (int i = 0; i < 4; ++i)
        #pragma unroll
        for (int j = 0; j < 4; ++j)
            acc[i][j] = (f32x4){0.f, 0.f, 0.f, 0.f};

    const __bf16* gsrc = (wid == 0) ? Ah : (wid == 1) ? Al : (wid == 2) ? Bh : Bl;
    __bf16* sdst = (wid == 0) ? sAh : (wid == 1) ? sAl : (wid == 2) ? sBh : sBl;
    const int gbase = (wid < 2) ? m0 : n0;
    const int grow = gbase + (lane >> 2);
    const int gcol = (lane & 3) * 8;

    const int arow = wr * 64 + (lane & 15);
    const int brow = wc * 64 + (lane & 15);
    const int koff = (lane >> 4) * 8;

    for (int k0 = 0; k0 < CH; k0 += 32) {
        #pragma unroll
        for (int i = 0; i < 8; ++i) {
            const __bf16* g = gsrc + (size_t)(grow + i * 16) * CH + k0 + gcol;
            __builtin_amdgcn_global_load_lds((gvoid_t*)g,
                                             (lvoid_t*)(sdst + i * 512),
                                             16, 0, 0);
        }
        __syncthreads();

        bf16x8 a_h[4], a_l[4], b_h[4], b_l[4];
        #pragma unroll
        for (int f = 0; f < 4; ++f) {
            a_h[f] = *(const bf16x8*)&sAh[(arow + f * 16) * 32 + koff];
            a_l[f] = *(const bf16x8*)&sAl[(arow + f * 16) * 32 + koff];
            b_h[f] = *(const bf16x8*)&sBh[(brow + f * 16) * 32 + koff];
            b_l[f] = *(const bf16x8*)&sBl[(brow + f * 16) * 32 + koff];
        }
        #pragma unroll
        for (int i = 0; i < 4; ++i)
            #pragma unroll
            for (int j = 0; j < 4; ++j) {
                acc[i][j] = __builtin_amdgcn_mfma_f32_16x16x32_bf16(a_h[i], b_l[j], acc[i][j], 0, 0, 0);
                acc[i][j] = __builtin_amdgcn_mfma_f32_16x16x32_bf16(a_l[i], b_h[j], acc[i][j], 0, 0, 0);
                acc[i][j] = __builtin_amdgcn_mfma_f32_16x16x32_bf16(a_h[i], b_h[j], acc[i][j], 0, 0, 0);
            }
        __syncthreads();
    }

    const int crow = (lane >> 4) * 4;
    const int ccol = lane & 15;

    if (EPI == 1) {
        #pragma unroll
        for (int i = 0; i < 4; ++i) {
            #pragma unroll
            for (int j = 0; j < 4; ++j) {
                const int n = n0 + wc * 64 + j * 16 + ccol;
                const float bv = bias[n];
                #pragma unroll
                for (int r = 0; r < 4; ++r) {
                    const int m = m0 + wr * 64 + i * 16 + crow + r;
                    outp[(size_t)m * CH + n] = acc[i][j][r] + bv;
                }
            }
        }
    } else {
        // wave's 64 cols = exactly one (sec, head) group; LN over d within wave
        const int nblk = n0 + wc * 64;
        const int sec = nblk >> 10;           // 0=q 1=k 2=v
        const int h = (nblk & 1023) >> 6;
        float bv[4];
        #pragma unroll
        for (int j = 0; j < 4; ++j) bv[j] = bias[nblk + j * 16 + ccol];

        if (sec < 2) {
            const float* gp = (sec == 0) ? qg : kg;
            const float* bp = (sec == 0) ? qb_ : kb_;
            float g4[4], b4[4];
            #pragma unroll
            for (int j = 0; j < 4; ++j) { g4[j] = gp[j*16+ccol]; b4[j] = bp[j*16+ccol]; }
            const float scale = (sec == 0) ? 0.125f : 1.0f;
            _Float16* dst = (sec == 0) ? qf : kf;
            #pragma unroll
            for (int i = 0; i < 4; ++i) {
                #pragma unroll
                for (int r = 0; r < 4; ++r) {
                    const int m = m0 + wr * 64 + i * 16 + crow + r;
                    const int b_ = m >> 10, nn = m & 1023;
                    float vals[4], s = 0.f, q2 = 0.f;
                    #pragma unroll
                    for (int j = 0; j < 4; ++j) {
                        vals[j] = acc[i][j][r] + bv[j];
                        s += vals[j]; q2 += vals[j] * vals[j];
                    }
                    #pragma unroll
                    for (int o = 1; o < 16; o <<= 1) {
                        s  += __shfl_xor(s, o, 64);
                        q2 += __shfl_xor(q2, o, 64);
                    }
                    const float mean = s * 0.015625f;
                    const float var = q2 * 0.015625f - mean * mean;
                    const float rstd = rsqrtf(var + 1e-5f);
                    #pragma unroll
                    for (int j = 0; j < 4; ++j) {
                        const float y = ((vals[j] - mean) * rstd * g4[j] + b4[j]) * scale;
                        dst[((size_t)(b_ * NH + h) * SQ + nn) * HD + j * 16 + ccol] = (_Float16)y;
                    }
                }
            }
        } else {
            // v: no LN, store transposed [B,H,D,N] fp16, pack 4 rows
            #pragma unroll
            for (int i = 0; i < 4; ++i) {
                const int m0r = m0 + wr * 64 + i * 16 + crow;
                const int b_ = m0r >> 10, nn0 = m0r & 1023;
                #pragma unroll
                for (int j = 0; j < 4; ++j) {
                    f16x4 tmp;
                    #pragma unroll
                    for (int r = 0; r < 4; ++r) tmp[r] = (_Float16)(acc[i][j][r] + bv[j]);
                    *(f16x4*)&vTf[((size_t)(b_ * NH + h) * HD + j * 16 + ccol) * SQ + nn0] = tmp;
                }
            }
        }
    }
}

// ---------- fused QK^T + softmax(no-max: |logit|<=8 rigorous) + weights + PV ----------
__global__ __launch_bounds__(256) void k_attn(
    const _Float16* __restrict__ q, const _Float16* __restrict__ k,
    const _Float16* __restrict__ vT, float* __restrict__ W,
    __bf16* __restrict__ oph, __bf16* __restrict__ opl)
{
    __shared__ _Float16 Pl[4][16][48];   // per-wave P staging, 96B row stride
    const int bh = blockIdx.y;
    const int wid = threadIdx.x >> 6, lane = threadIdx.x & 63;
    const int row0 = blockIdx.x * 64 + wid * 16;   // this wave's 16 q-rows
    const int lr = lane & 15, lg = lane >> 4;

    const _Float16* qh = q  + (size_t)bh * SQ * HD;
    const _Float16* kh = k  + (size_t)bh * SQ * HD;
    const _Float16* vh = vT + (size_t)bh * HD * SQ;

    // Q A-fragments (16 rows x 64 k), 2 chunks of K=32
    f16x8 qa[2];
    #pragma unroll
    for (int c = 0; c < 2; ++c)
        qa[c] = *(const f16x8*)&qh[(size_t)(row0 + lr) * HD + c * 32 + lg * 8];

    // ---- phase 1: l[row] = sum_j exp(s) ----
    float lsum[4] = {0.f, 0.f, 0.f, 0.f};
    #pragma unroll 4
    for (int ct = 0; ct < 64; ++ct) {
        const f16x8 kb0 = *(const f16x8*)&kh[(size_t)(ct * 16 + lr) * HD + lg * 8];
        const f16x8 kb1 = *(const f16x8*)&kh[(size_t)(ct * 16 + lr) * HD + 32 + lg * 8];
        f32x4 s = (f32x4){0.f, 0.f, 0.f, 0.f};
        s = __builtin_amdgcn_mfma_f32_16x16x32_f16(qa[0], kb0, s, 0, 0, 0);
        s = __builtin_amdgcn_mfma_f32_16x16x32_f16(qa[1], kb1, s, 0, 0, 0);
        #pragma unroll
        for (int r = 0; r < 4; ++r) lsum[r] += __expf(s[r]);
    }
    #pragma unroll
    for (int r = 0; r < 4; ++r) {
        #pragma unroll
        for (int o = 1; o < 16; o <<= 1) lsum[r] += __shfl_xor(lsum[r], o, 64);
        lsum[r] = 1.0f / lsum[r];     // invl for rows lg*4+r
    }

    // ---- phase 2: recompute s, write weights, PV ----
    float* Wr = W + (size_t)bh * SQ * SQ;
    f32x4 opv[4];
    #pragma unroll
    for (int dt = 0; dt < 4; ++dt) opv[dt] = (f32x4){0.f, 0.f, 0.f, 0.f};

    for (int jc = 0; jc < 32; ++jc) {          // 32-col chunks
        #pragma unroll
        for (int t = 0; t < 2; ++t) {
            const int ct = jc * 2 + t;
            const f16x8 kb0 = *(const f16x8*)&kh[(size_t)(ct * 16 + lr) * HD + lg * 8];
            const f16x8 kb1 = *(const f16x8*)&kh[(size_t)(ct * 16 + lr) * HD + 32 + lg * 8];
            f32x4 s = (f32x4){0.f, 0.f, 0.f, 0.f};
            s = __builtin_amdgcn_mfma_f32_16x16x32_f16(qa[0], kb0, s, 0, 0, 0);
            s = __builtin_amdgcn_mfma_f32_16x16x32_f16(qa[1], kb1, s, 0, 0, 0);
            #pragma unroll
            for (int r = 0; r < 4; ++r) {
                const float p = __expf(s[r]) * lsum[r];
                Wr[(size_t)(row0 + lg * 4 + r) * SQ + ct * 16 + lr] = p;
                Pl[wid][lg * 4 + r][t * 16 + lr] = (_Float16)p;
            }
        }
        asm volatile("" ::: "memory");   // keep ds_writes before ds_read
        const f16x8 pa = *(const f16x8*)&Pl[wid][lr][lg * 8];
        #pragma unroll
        for (int dt = 0; dt < 4; ++dt) {
            const f16x8 vb = *(const f16x8*)&vh[(size_t)(dt * 16 + lr) * SQ + jc * 32 + lg * 8];
            opv[dt] = __builtin_amdgcn_mfma_f32_16x16x32_f16(pa, vb, opv[dt], 0, 0, 0);
        }
    }

    // epilogue: write attention output as bf16 hi/lo [B,N,C]
    const int b_ = bh >> 4, h = bh & 15;
    #pragma unroll
    for (int dt = 0; dt < 4; ++dt) {
        #pragma unroll
        for (int r = 0; r < 4; ++r) {
            const int row = row0 + lg * 4 + r;
            const size_t idx = ((size_t)(b_ * SQ + row)) * CH + h * HD + dt * 16 + lr;
            const float val = opv[dt][r];
            const __bf16 hh = (__bf16)val;
            oph[idx] = hh;
            opl[idx] = (__bf16)(val - (float)hh);
        }
    }
}

extern "C" void kernel_launch(void* const* d_in, const int* in_sizes, int n_in,
                              void* d_out, int out_size, void* d_ws, size_t ws_size,
                              hipStream_t stream)
{
    const float* x    = (const float*)d_in[0];
    const float* Wqkv = (const float*)d_in[1];
    const float* bqkv = (const float*)d_in[2];
    const float* qg   = (const float*)d_in[3];
    const float* qb   = (const float*)d_in[4];
    const float* kg   = (const float*)d_in[5];
    const float* kb   = (const float*)d_in[6];
    const float* Wp   = (const float*)d_in[7];
    const float* bp   = (const float*)d_in[8];

    float* out     = (float*)d_out;                       // [B,N,C]
    float* weights = out + (size_t)NB * SQ * CH;          // [B,H,N,N]

    // ws layout (MB): xh 0-8, xl 8-16, wqh 16-22, wql 22-28, wph 28-30, wpl 30-32,
    //                 q 32-40, k 40-48, vT 48-56, oph 56-64, opl 64-72
    char* w = (char*)d_ws;
    __bf16*   xh  = (__bf16*)w;
    __bf16*   xl  = (__bf16*)(w + (((size_t)8)  << 20));
    __bf16*   wqh = (__bf16*)(w + (((size_t)16) << 20));
    __bf16*   wql = (__bf16*)(w + (((size_t)22) << 20));
    __bf16*   wph = (__bf16*)(w + (((size_t)28) << 20));
    __bf16*   wpl = (__bf16*)(w + (((size_t)30) << 20));
    _Float16* qf  = (_Float16*)(w + (((size_t)32) << 20));
    _Float16* kf  = (_Float16*)(w + (((size_t)40) << 20));
    _Float16* vTf = (_Float16*)(w + (((size_t)48) << 20));
    __bf16*   oph = (__bf16*)(w + (((size_t)56) << 20));
    __bf16*   opl = (__bf16*)(w + (((size_t)64) << 20));

    // 0) split fp32 inputs to bf16 hi/lo
    k_split<<<(NB*SQ*CH/4 + 255)/256, 256, 0, stream>>>(x, xh, xl, NB*SQ*CH/4);
    k_split<<<(3*CH*CH/4 + 255)/256, 256, 0, stream>>>(Wqkv, wqh, wql, 3*CH*CH/4);
    k_split<<<(CH*CH/4 + 255)/256, 256, 0, stream>>>(Wp, wph, wpl, CH*CH/4);

    // 1) qkv GEMM + fused bias+LN epilogue -> q,k fp16 (LN'd), vT fp16
    k_mfma_gemm<0><<<dim3(24, 32), 256, 0, stream>>>(
        xh, xl, wqh, wql, bqkv, nullptr, qf, kf, vTf, qg, qb, kg, kb);

    // 2) fused attention: QK^T + exact softmax + weights write + PV
    k_attn<<<dim3(16, NB * NH), 256, 0, stream>>>(qf, kf, vTf, weights, oph, opl);

    // 3) proj GEMM
    k_mfma_gemm<1><<<dim3(8, 32), 256, 0, stream>>>(
        oph, opl, wph, wpl, bp, out, nullptr, nullptr, nullptr,
        nullptr, nullptr, nullptr, nullptr);
}

// Round 6
// 335.935 us; speedup vs baseline: 3.3388x; 1.0585x over previous
//
#include <hip/hip_runtime.h>
#include <math.h>

#define NH 16          // heads
#define HD 64          // head dim
#define NB 4           // batch
#define SQ 1024        // seq len
#define CH 1024        // channels

typedef __bf16   bf16x8 __attribute__((ext_vector_type(8)));
typedef __bf16   bf16x4 __attribute__((ext_vector_type(4)));
typedef _Float16 f16x8  __attribute__((ext_vector_type(8)));
typedef _Float16 f16x4  __attribute__((ext_vector_type(4)));
typedef float    f32x4  __attribute__((ext_vector_type(4)));

typedef const __attribute__((address_space(1))) void gvoid_t;
typedef __attribute__((address_space(3))) void lvoid_t;

// ---------- split fp32 -> bf16 hi/lo ----------
__global__ __launch_bounds__(256) void k_split(
    const float* __restrict__ in, __bf16* __restrict__ hi,
    __bf16* __restrict__ lo, int n4)
{
    const int idx = blockIdx.x * 256 + threadIdx.x;
    if (idx >= n4) return;
    const float4 v = ((const float4*)in)[idx];
    bf16x4 h, l;
    h[0] = (__bf16)v.x; l[0] = (__bf16)(v.x - (float)h[0]);
    h[1] = (__bf16)v.y; l[1] = (__bf16)(v.y - (float)h[1]);
    h[2] = (__bf16)v.z; l[2] = (__bf16)(v.z - (float)h[2]);
    h[3] = (__bf16)v.w; l[3] = (__bf16)(v.w - (float)h[3]);
    ((bf16x4*)hi)[idx] = h;
    ((bf16x4*)lo)[idx] = l;
}

// ---------- split-bf16 MFMA GEMM: C = A @ B^T (+bias)
// EPI 0: fused LN epilogue -> q,k fp16 [B,H,N,D] (LN'd, q scaled), vT fp16 [B,H,D,N]
// EPI 1: plain fp32 out [M][1024] ----------
template<int EPI>
__global__ __launch_bounds__(256) void k_mfma_gemm(
    const __bf16* __restrict__ Ah, const __bf16* __restrict__ Al,
    const __bf16* __restrict__ Bh, const __bf16* __restrict__ Bl,
    const float* __restrict__ bias, float* __restrict__ outp,
    _Float16* __restrict__ qf, _Float16* __restrict__ kf, _Float16* __restrict__ vTf,
    const float* __restrict__ qg, const float* __restrict__ qb_,
    const float* __restrict__ kg, const float* __restrict__ kb_)
{
    __shared__ __align__(16) __bf16 sAh[128 * 32];
    __shared__ __align__(16) __bf16 sAl[128 * 32];
    __shared__ __align__(16) __bf16 sBh[128 * 32];
    __shared__ __align__(16) __bf16 sBl[128 * 32];

    const int tid = threadIdx.x;
    const int wid = tid >> 6, lane = tid & 63;
    const int wr = wid >> 1, wc = wid & 1;
    const int m0 = blockIdx.y * 128, n0 = blockIdx.x * 128;

    f32x4 acc[4][4];
    #pragma unroll
    for (int i = 0; i < 4; ++i)
        #pragma unroll
        for (int j = 0; j < 4; ++j)
            acc[i][j] = (f32x4){0.f, 0.f, 0.f, 0.f};

    const __bf16* gsrc = (wid == 0) ? Ah : (wid == 1) ? Al : (wid == 2) ? Bh : Bl;
    __bf16* sdst = (wid == 0) ? sAh : (wid == 1) ? sAl : (wid == 2) ? sBh : sBl;
    const int gbase = (wid < 2) ? m0 : n0;
    const int grow = gbase + (lane >> 2);
    const int gcol = (lane & 3) * 8;

    const int arow = wr * 64 + (lane & 15);
    const int brow = wc * 64 + (lane & 15);
    const int koff = (lane >> 4) * 8;

    for (int k0 = 0; k0 < CH; k0 += 32) {
        #pragma unroll
        for (int i = 0; i < 8; ++i) {
            const __bf16* g = gsrc + (size_t)(grow + i * 16) * CH + k0 + gcol;
            __builtin_amdgcn_global_load_lds((gvoid_t*)g,
                                             (lvoid_t*)(sdst + i * 512),
                                             16, 0, 0);
        }
        __syncthreads();

        bf16x8 a_h[4], a_l[4], b_h[4], b_l[4];
        #pragma unroll
        for (int f = 0; f < 4; ++f) {
            a_h[f] = *(const bf16x8*)&sAh[(arow + f * 16) * 32 + koff];
            a_l[f] = *(const bf16x8*)&sAl[(arow + f * 16) * 32 + koff];
            b_h[f] = *(const bf16x8*)&sBh[(brow + f * 16) * 32 + koff];
            b_l[f] = *(const bf16x8*)&sBl[(brow + f * 16) * 32 + koff];
        }
        #pragma unroll
        for (int i = 0; i < 4; ++i)
            #pragma unroll
            for (int j = 0; j < 4; ++j) {
                acc[i][j] = __builtin_amdgcn_mfma_f32_16x16x32_bf16(a_h[i], b_l[j], acc[i][j], 0, 0, 0);
                acc[i][j] = __builtin_amdgcn_mfma_f32_16x16x32_bf16(a_l[i], b_h[j], acc[i][j], 0, 0, 0);
                acc[i][j] = __builtin_amdgcn_mfma_f32_16x16x32_bf16(a_h[i], b_h[j], acc[i][j], 0, 0, 0);
            }
        __syncthreads();
    }

    const int crow = (lane >> 4) * 4;
    const int ccol = lane & 15;

    if (EPI == 1) {
        #pragma unroll
        for (int i = 0; i < 4; ++i) {
            #pragma unroll
            for (int j = 0; j < 4; ++j) {
                const int n = n0 + wc * 64 + j * 16 + ccol;
                const float bv = bias[n];
                #pragma unroll
                for (int r = 0; r < 4; ++r) {
                    const int m = m0 + wr * 64 + i * 16 + crow + r;
                    outp[(size_t)m * CH + n] = acc[i][j][r] + bv;
                }
            }
        }
    } else {
        // wave's 64 cols = exactly one (sec, head) group; LN over d within wave
        const int nblk = n0 + wc * 64;
        const int sec = nblk >> 10;           // 0=q 1=k 2=v
        const int h = (nblk & 1023) >> 6;
        float bv[4];
        #pragma unroll
        for (int j = 0; j < 4; ++j) bv[j] = bias[nblk + j * 16 + ccol];

        if (sec < 2) {
            const float* gp = (sec == 0) ? qg : kg;
            const float* bp = (sec == 0) ? qb_ : kb_;
            float g4[4], b4[4];
            #pragma unroll
            for (int j = 0; j < 4; ++j) { g4[j] = gp[j*16+ccol]; b4[j] = bp[j*16+ccol]; }
            const float scale = (sec == 0) ? 0.125f : 1.0f;
            _Float16* dst = (sec == 0) ? qf : kf;
            #pragma unroll
            for (int i = 0; i < 4; ++i) {
                #pragma unroll
                for (int r = 0; r < 4; ++r) {
                    const int m = m0 + wr * 64 + i * 16 + crow + r;
                    const int b_ = m >> 10, nn = m & 1023;
                    float vals[4], s = 0.f, q2 = 0.f;
                    #pragma unroll
                    for (int j = 0; j < 4; ++j) {
                        vals[j] = acc[i][j][r] + bv[j];
                        s += vals[j]; q2 += vals[j] * vals[j];
                    }
                    #pragma unroll
                    for (int o = 1; o < 16; o <<= 1) {
                        s  += __shfl_xor(s, o, 64);
                        q2 += __shfl_xor(q2, o, 64);
                    }
                    const float mean = s * 0.015625f;
                    const float var = q2 * 0.015625f - mean * mean;
                    const float rstd = rsqrtf(var + 1e-5f);
                    #pragma unroll
                    for (int j = 0; j < 4; ++j) {
                        const float y = ((vals[j] - mean) * rstd * g4[j] + b4[j]) * scale;
                        dst[((size_t)(b_ * NH + h) * SQ + nn) * HD + j * 16 + ccol] = (_Float16)y;
                    }
                }
            }
        } else {
            // v: no LN, store transposed [B,H,D,N] fp16, pack 4 rows
            #pragma unroll
            for (int i = 0; i < 4; ++i) {
                const int m0r = m0 + wr * 64 + i * 16 + crow;
                const int b_ = m0r >> 10, nn0 = m0r & 1023;
                #pragma unroll
                for (int j = 0; j < 4; ++j) {
                    f16x4 tmp;
                    #pragma unroll
                    for (int r = 0; r < 4; ++r) tmp[r] = (_Float16)(acc[i][j][r] + bv[j]);
                    *(f16x4*)&vTf[((size_t)(b_ * NH + h) * HD + j * 16 + ccol) * SQ + nn0] = tmp;
                }
            }
        }
    }
}

// ---------- fused QK^T + softmax(no-max: |logit|<=8 rigorous) + weights + PV ----------
// Swapped-operand QK^T: s_tile = mfma(K_frag, Q_frag) -> lane holds 4 consecutive
// k-cols for one q-row => f32x4 NT weights stores, f16x4 LDS P stores.
// 1D grid with XCD-clustering swizzle: all 16 blocks of one bh share linear%8.
__global__ __launch_bounds__(256) void k_attn(
    const _Float16* __restrict__ q, const _Float16* __restrict__ k,
    const _Float16* __restrict__ vT, float* __restrict__ W,
    __bf16* __restrict__ oph, __bf16* __restrict__ opl)
{
    __shared__ _Float16 Pl[4][16][32];
    const int L = blockIdx.x;
    const int bh   = (L & 7) * 8 + ((L >> 3) >> 4);   // same bh -> same linear%8 -> same XCD
    const int xblk = (L >> 3) & 15;
    const int wid = threadIdx.x >> 6, lane = threadIdx.x & 63;
    const int row0 = xblk * 64 + wid * 16;            // this wave's 16 q-rows
    const int lr = lane & 15, lg = lane >> 4;

    const _Float16* qh = q  + (size_t)bh * SQ * HD;
    const _Float16* kh = k  + (size_t)bh * SQ * HD;
    const _Float16* vh = vT + (size_t)bh * HD * SQ;

    // Q B-fragments (B[d][q=lr]): Q rows of this wave
    const f16x8 qb0 = *(const f16x8*)&qh[(size_t)(row0 + lr) * HD + lg * 8];
    const f16x8 qb1 = *(const f16x8*)&qh[(size_t)(row0 + lr) * HD + 32 + lg * 8];

    // ---- phase 1: per-q row sums of exp(s) ----
    float lp = 0.f;
    #pragma unroll 4
    for (int kt = 0; kt < 64; ++kt) {
        const f16x8 ka0 = *(const f16x8*)&kh[(size_t)(kt * 16 + lr) * HD + lg * 8];
        const f16x8 ka1 = *(const f16x8*)&kh[(size_t)(kt * 16 + lr) * HD + 32 + lg * 8];
        f32x4 s = (f32x4){0.f, 0.f, 0.f, 0.f};
        s = __builtin_amdgcn_mfma_f32_16x16x32_f16(ka0, qb0, s, 0, 0, 0);
        s = __builtin_amdgcn_mfma_f32_16x16x32_f16(ka1, qb1, s, 0, 0, 0);
        #pragma unroll
        for (int r = 0; r < 4; ++r) lp += __expf(s[r]);
    }
    lp += __shfl_xor(lp, 16, 64);
    lp += __shfl_xor(lp, 32, 64);
    const float invl = 1.0f / lp;       // for q = row0 + lr

    // ---- phase 2: recompute s, write weights (f32x4 NT), PV ----
    float* Wr = W + (size_t)bh * SQ * SQ;
    f32x4 opv[4];
    #pragma unroll
    for (int dt = 0; dt < 4; ++dt) opv[dt] = (f32x4){0.f, 0.f, 0.f, 0.f};

    for (int jc = 0; jc < 32; ++jc) {          // 32-k chunks
        #pragma unroll
        for (int t = 0; t < 2; ++t) {
            const int kt = jc * 2 + t;
            const f16x8 ka0 = *(const f16x8*)&kh[(size_t)(kt * 16 + lr) * HD + lg * 8];
            const f16x8 ka1 = *(const f16x8*)&kh[(size_t)(kt * 16 + lr) * HD + 32 + lg * 8];
            f32x4 s = (f32x4){0.f, 0.f, 0.f, 0.f};
            s = __builtin_amdgcn_mfma_f32_16x16x32_f16(ka0, qb0, s, 0, 0, 0);
            s = __builtin_amdgcn_mfma_f32_16x16x32_f16(ka1, qb1, s, 0, 0, 0);
            f32x4 wv;
            f16x4 pv;
            #pragma unroll
            for (int r = 0; r < 4; ++r) {
                wv[r] = __expf(s[r]) * invl;
                pv[r] = (_Float16)wv[r];
            }
            __builtin_nontemporal_store(wv,
                (f32x4*)&Wr[(size_t)(row0 + lr) * SQ + kt * 16 + lg * 4]);
            *(f16x4*)&Pl[wid][lr][t * 16 + lg * 4] = pv;
        }
        asm volatile("" ::: "memory");   // keep ds_writes before ds_read
        const f16x8 pa = *(const f16x8*)&Pl[wid][lr][lg * 8];
        #pragma unroll
        for (int dt = 0; dt < 4; ++dt) {
            const f16x8 vb = *(const f16x8*)&vh[(size_t)(dt * 16 + lr) * SQ + jc * 32 + lg * 8];
            opv[dt] = __builtin_amdgcn_mfma_f32_16x16x32_f16(pa, vb, opv[dt], 0, 0, 0);
        }
    }

    // epilogue: write attention output as bf16 hi/lo [B,N,C]
    const int b_ = bh >> 4, h = bh & 15;
    #pragma unroll
    for (int dt = 0; dt < 4; ++dt) {
        #pragma unroll
        for (int r = 0; r < 4; ++r) {
            const int row = row0 + lg * 4 + r;
            const size_t idx = ((size_t)(b_ * SQ + row)) * CH + h * HD + dt * 16 + lr;
            const float val = opv[dt][r];
            const __bf16 hh = (__bf16)val;
            oph[idx] = hh;
            opl[idx] = (__bf16)(val - (float)hh);
        }
    }
}

extern "C" void kernel_launch(void* const* d_in, const int* in_sizes, int n_in,
                              void* d_out, int out_size, void* d_ws, size_t ws_size,
                              hipStream_t stream)
{
    const float* x    = (const float*)d_in[0];
    const float* Wqkv = (const float*)d_in[1];
    const float* bqkv = (const float*)d_in[2];
    const float* qg   = (const float*)d_in[3];
    const float* qb   = (const float*)d_in[4];
    const float* kg   = (const float*)d_in[5];
    const float* kb   = (const float*)d_in[6];
    const float* Wp   = (const float*)d_in[7];
    const float* bp   = (const float*)d_in[8];

    float* out     = (float*)d_out;                       // [B,N,C]
    float* weights = out + (size_t)NB * SQ * CH;          // [B,H,N,N]

    // ws layout (MB): xh 0-8, xl 8-16, wqh 16-22, wql 22-28, wph 28-30, wpl 30-32,
    //                 q 32-40, k 40-48, vT 48-56, oph 56-64, opl 64-72
    char* w = (char*)d_ws;
    __bf16*   xh  = (__bf16*)w;
    __bf16*   xl  = (__bf16*)(w + (((size_t)8)  << 20));
    __bf16*   wqh = (__bf16*)(w + (((size_t)16) << 20));
    __bf16*   wql = (__bf16*)(w + (((size_t)22) << 20));
    __bf16*   wph = (__bf16*)(w + (((size_t)28) << 20));
    __bf16*   wpl = (__bf16*)(w + (((size_t)30) << 20));
    _Float16* qf  = (_Float16*)(w + (((size_t)32) << 20));
    _Float16* kf  = (_Float16*)(w + (((size_t)40) << 20));
    _Float16* vTf = (_Float16*)(w + (((size_t)48) << 20));
    __bf16*   oph = (__bf16*)(w + (((size_t)56) << 20));
    __bf16*   opl = (__bf16*)(w + (((size_t)64) << 20));

    // 0) split fp32 inputs to bf16 hi/lo
    k_split<<<(NB*SQ*CH/4 + 255)/256, 256, 0, stream>>>(x, xh, xl, NB*SQ*CH/4);
    k_split<<<(3*CH*CH/4 + 255)/256, 256, 0, stream>>>(Wqkv, wqh, wql, 3*CH*CH/4);
    k_split<<<(CH*CH/4 + 255)/256, 256, 0, stream>>>(Wp, wph, wpl, CH*CH/4);

    // 1) qkv GEMM + fused bias+LN epilogue -> q,k fp16 (LN'd), vT fp16
    k_mfma_gemm<0><<<dim3(24, 32), 256, 0, stream>>>(
        xh, xl, wqh, wql, bqkv, nullptr, qf, kf, vTf, qg, qb, kg, kb);

    // 2) fused attention: QK^T + exact softmax + weights write + PV
    k_attn<<<dim3(NB * NH * 16), 256, 0, stream>>>(qf, kf, vTf, weights, oph, opl);

    // 3) proj GEMM
    k_mfma_gemm<1><<<dim3(8, 32), 256, 0, stream>>>(
        oph, opl, wph, wpl, bp, out, nullptr, nullptr, nullptr,
        nullptr, nullptr, nullptr, nullptr);
}